// Round 1
// baseline (1104.951 us; speedup 1.0000x reference)
//
#include <hip/hip_runtime.h>

// Paged-attention decode, fp32, MI355X.
// B=32, Q_LEN=4, KV_LEN=4096, H_Q=32, H_KV=8, D=128, BLOCK_SIZE=16.
// Kernel 1: scatter new K/V rows into caches (harness restores inputs each launch).
// Kernel 2: one WG per (b, kv_head); flash-decode with online softmax.

#define BBATCH 32
#define QL 4
#define KVL 4096
#define HQ 32
#define HKV 8
#define DDIM 128
#define GQ 4           // HQ/HKV
#define BLK 16
#define BPS 256        // blocks per sequence
#define NP 16          // (g, qi) pairs per kv-head = GQ*QL
#define CHUNK 512
#define NCHUNK 8       // KVL/CHUNK
#define NT 512
#define PBS 20         // p_s row stride in floats (16 pairs + pad, keeps 16B align)

struct SMemMain {
    float p[CHUNK * PBS];   // 40960 B : per-chunk probabilities [token][pair]
    float q[NP * DDIM];     //  8192 B : scaled Q [pair][d]
    int   bt[BPS];          //  1024 B : block table row
    float red[8 * NP];      //   512 B : per-wave reduction scratch
    float fin[NP];          //    64 B : broadcast of reduced max/sum
};
union __align__(16) SMem {
    SMemMain m;
    float o[4 * NP * DDIM]; // 32768 B : epilogue partial-O slots (overlays p)
};

__global__ void scatter_kv(const float* __restrict__ knew,
                           const float* __restrict__ vnew,
                           const int* __restrict__ slots,
                           float* __restrict__ kc, float* __restrict__ vc) {
    const int i = blockIdx.x;        // token 0..127
    const int t = threadIdx.x;       // 0..255, each copies one float4
    const int slot = slots[i];
    const size_t dst = (size_t)slot * (HKV * DDIM) + t * 4;
    const size_t src = (size_t)i * (HKV * DDIM) + t * 4;
    *(float4*)(kc + dst) = *(const float4*)(knew + src);
    *(float4*)(vc + dst) = *(const float4*)(vnew + src);
}

__global__ void __launch_bounds__(NT, 2)
attn_kernel(const float* __restrict__ query,
            const float* __restrict__ kcache,
            const float* __restrict__ vcache,
            const int* __restrict__ btab,
            float* __restrict__ out) {
    __shared__ SMem sm;
    const int h = blockIdx.x;        // kv head
    const int b = blockIdx.y;        // batch
    const int tid = threadIdx.x;
    const int lane = tid & 63;
    const int wave = tid >> 6;
    const int d4 = tid & 31;         // dim-quad index (PV role, Q load, epilogue)

    // Stage block-table row and scaled Q into LDS.
    if (tid < BPS) sm.m.bt[tid] = btab[b * BPS + tid];
    {
        const int pr = tid >> 5;     // 0..15
        const int g = pr >> 2, qi = pr & 3;
        const float sc = 0.088388347648318447f;   // 1/sqrt(128)
        const float4 qv = *(const float4*)(query + (size_t)(b * QL + qi) * (HQ * DDIM)
                                           + (h * GQ + g) * DDIM + d4 * 4);
        float4 qs; qs.x = qv.x * sc; qs.y = qv.y * sc; qs.z = qv.z * sc; qs.w = qv.w * sc;
        *(float4*)&sm.m.q[pr * DDIM + d4 * 4] = qs;
    }
    __syncthreads();

    float m_r[NP], l_r[NP], o_r[NP][4];
#pragma unroll
    for (int i = 0; i < NP; ++i) {
        m_r[i] = -__builtin_inff(); l_r[i] = 0.f;
        o_r[i][0] = 0.f; o_r[i][1] = 0.f; o_r[i][2] = 0.f; o_r[i][3] = 0.f;
    }

    for (int c = 0; c < NCHUNK; ++c) {
        // ---------------- QK: thread owns one token ----------------
        const int p = c * CHUNK + tid;
        const float4* kp = (const float4*)(kcache
            + (((size_t)sm.m.bt[p >> 4] * BLK + (p & 15)) * HKV + h) * DDIM);
        float s[NP];
#pragma unroll
        for (int i = 0; i < NP; ++i) s[i] = 0.f;
#pragma unroll 1
        for (int gqi = 0; gqi < 4; ++gqi) {          // 4 groups of 8 float4s
            float4 k4[8];
#pragma unroll
            for (int j = 0; j < 8; ++j) k4[j] = kp[gqi * 8 + j];
#pragma unroll
            for (int j = 0; j < 8; ++j) {
                const int dbase = (gqi * 8 + j) * 4;
#pragma unroll
                for (int pr = 0; pr < NP; ++pr) {
                    const float4 q4 = *(const float4*)&sm.m.q[pr * DDIM + dbase];
                    s[pr] = fmaf(k4[j].x, q4.x,
                            fmaf(k4[j].y, q4.y,
                            fmaf(k4[j].z, q4.z,
                            fmaf(k4[j].w, q4.w, s[pr]))));
                }
            }
        }
        // Causal mask: key pos p masked for query qi iff p - qi > KVL - QL.
        const int excess = p - (KVL - QL);
        if (excess > 0) {
#pragma unroll
            for (int pr = 0; pr < NP; ++pr)
                if ((pr & 3) < excess) s[pr] = -__builtin_inff();
        }
        // Workgroup max per pair.
        float w16[NP];
#pragma unroll
        for (int i = 0; i < NP; ++i) w16[i] = s[i];
#pragma unroll
        for (int off = 32; off >= 1; off >>= 1)
#pragma unroll
            for (int i = 0; i < NP; ++i)
                w16[i] = fmaxf(w16[i], __shfl_xor(w16[i], off, 64));
        if (lane == 0) {
#pragma unroll
            for (int i = 0; i < NP; ++i) sm.m.red[wave * NP + i] = w16[i];
        }
        __syncthreads();
        if (tid < NP) {
            float v = sm.m.red[tid];
#pragma unroll
            for (int w = 1; w < 8; ++w) v = fmaxf(v, sm.m.red[w * NP + tid]);
            sm.m.fin[tid] = v;
        }
        __syncthreads();
        float alpha[NP];
#pragma unroll
        for (int i = 0; i < NP; ++i) {
            const float M = fmaxf(m_r[i], sm.m.fin[i]);
            alpha[i] = __expf(m_r[i] - M);
            m_r[i] = M;
        }
        float pv[NP];
#pragma unroll
        for (int i = 0; i < NP; ++i) pv[i] = __expf(s[i] - m_r[i]);
        *(float4*)&sm.m.p[tid * PBS + 0]  = make_float4(pv[0], pv[1], pv[2], pv[3]);
        *(float4*)&sm.m.p[tid * PBS + 4]  = make_float4(pv[4], pv[5], pv[6], pv[7]);
        *(float4*)&sm.m.p[tid * PBS + 8]  = make_float4(pv[8], pv[9], pv[10], pv[11]);
        *(float4*)&sm.m.p[tid * PBS + 12] = make_float4(pv[12], pv[13], pv[14], pv[15]);
        // Workgroup sum per pair.
#pragma unroll
        for (int off = 32; off >= 1; off >>= 1)
#pragma unroll
            for (int i = 0; i < NP; ++i)
                pv[i] += __shfl_xor(pv[i], off, 64);
        if (lane == 0) {
#pragma unroll
            for (int i = 0; i < NP; ++i) sm.m.red[wave * NP + i] = pv[i];
        }
        __syncthreads();
        if (tid < NP) {
            float v = sm.m.red[tid];
#pragma unroll
            for (int w = 1; w < 8; ++w) v += sm.m.red[w * NP + tid];
            sm.m.fin[tid] = v;
        }
        __syncthreads();
#pragma unroll
        for (int i = 0; i < NP; ++i) l_r[i] = l_r[i] * alpha[i] + sm.m.fin[i];

        // ---------------- PV: thread owns (token-group, dim-quad) ----------------
#pragma unroll
        for (int i = 0; i < NP; ++i) {
            o_r[i][0] *= alpha[i]; o_r[i][1] *= alpha[i];
            o_r[i][2] *= alpha[i]; o_r[i][3] *= alpha[i];
        }
        const int tg = tid >> 5;     // 16 token-groups x 32 tokens
#pragma unroll 1
        for (int jo = 0; jo < 4; ++jo) {
            float4 v4[8]; const float* pp[8];
#pragma unroll
            for (int j = 0; j < 8; ++j) {
                const int tl = tg * 32 + jo * 8 + j;
                const int pa = c * CHUNK + tl;
                const float* vp = vcache
                    + (((size_t)sm.m.bt[pa >> 4] * BLK + (pa & 15)) * HKV + h) * DDIM;
                v4[j] = *(const float4*)(vp + d4 * 4);
                pp[j] = &sm.m.p[tl * PBS];
            }
#pragma unroll
            for (int j = 0; j < 8; ++j) {
                const float4 p0 = *(const float4*)(pp[j] + 0);
                const float4 p1 = *(const float4*)(pp[j] + 4);
                const float4 p2 = *(const float4*)(pp[j] + 8);
                const float4 p3 = *(const float4*)(pp[j] + 12);
                const float pj[NP] = { p0.x, p0.y, p0.z, p0.w, p1.x, p1.y, p1.z, p1.w,
                                       p2.x, p2.y, p2.z, p2.w, p3.x, p3.y, p3.z, p3.w };
#pragma unroll
                for (int i = 0; i < NP; ++i) {
                    o_r[i][0] = fmaf(pj[i], v4[j].x, o_r[i][0]);
                    o_r[i][1] = fmaf(pj[i], v4[j].y, o_r[i][1]);
                    o_r[i][2] = fmaf(pj[i], v4[j].z, o_r[i][2]);
                    o_r[i][3] = fmaf(pj[i], v4[j].w, o_r[i][3]);
                }
            }
        }
    }

    // ---------------- Epilogue: reduce over 16 token-groups ----------------
    __syncthreads();                 // p_s dead; sm.o overlays it
#pragma unroll
    for (int i = 0; i < NP; ++i)
#pragma unroll
        for (int j = 0; j < 4; ++j)
            o_r[i][j] += __shfl_xor(o_r[i][j], 32, 64);   // merge tg pairs in-wave

    const int slot = wave & 3;
    float* ob = sm.o + slot * (NP * DDIM);
    if (wave < 4 && lane < 32) {
#pragma unroll
        for (int i = 0; i < NP; ++i)
            *(float4*)&ob[i * DDIM + d4 * 4] =
                make_float4(o_r[i][0], o_r[i][1], o_r[i][2], o_r[i][3]);
    }
    __syncthreads();
    if (wave >= 4 && lane < 32) {
#pragma unroll
        for (int i = 0; i < NP; ++i) {
            float4 t = *(float4*)&ob[i * DDIM + d4 * 4];
            t.x += o_r[i][0]; t.y += o_r[i][1]; t.z += o_r[i][2]; t.w += o_r[i][3];
            *(float4*)&ob[i * DDIM + d4 * 4] = t;
        }
    }
    __syncthreads();
    {
        const int pair = tid >> 5;   // 0..15
        const int g = pair >> 2, qi = pair & 3;
        float4 acc = make_float4(0.f, 0.f, 0.f, 0.f);
#pragma unroll
        for (int w2 = 0; w2 < 4; ++w2) {
            const float4 t = *(const float4*)&sm.o[w2 * NP * DDIM + pair * DDIM + d4 * 4];
            acc.x += t.x; acc.y += t.y; acc.z += t.z; acc.w += t.w;
        }
        const float inv = 1.0f / l_r[pair];
        acc.x *= inv; acc.y *= inv; acc.z *= inv; acc.w *= inv;
        *(float4*)(out + (size_t)(b * QL + qi) * (HQ * DDIM)
                   + (h * GQ + g) * DDIM + d4 * 4) = acc;
    }
}

extern "C" void kernel_launch(void* const* d_in, const int* in_sizes, int n_in,
                              void* d_out, int out_size, void* d_ws, size_t ws_size,
                              hipStream_t stream) {
    (void)in_sizes; (void)n_in; (void)out_size; (void)d_ws; (void)ws_size;
    const float* query = (const float*)d_in[0];
    const float* knew  = (const float*)d_in[1];
    const float* vnew  = (const float*)d_in[2];
    float* kcache      = (float*)d_in[3];   // mutated; harness restores pristine inputs
    float* vcache      = (float*)d_in[4];
    const int* btab    = (const int*)d_in[5];
    const int* slots   = (const int*)d_in[6];
    float* out         = (float*)d_out;

    scatter_kv<<<dim3(BBATCH * QL), dim3(256), 0, stream>>>(knew, vnew, slots, kcache, vcache);
    attn_kernel<<<dim3(HKV, BBATCH), dim3(NT), 0, stream>>>(query, kcache, vcache, btab, out);
}